// Round 2
// baseline (2444.802 us; speedup 1.0000x reference)
//
#include <hip/hip_runtime.h>
#include <math.h>

#define TT 2048
#define HH 2048
#define NSTEP 16
#define EPSF 1e-8f
#define BETA 0.1f
#define TSPLIT 8
#define TCHUNK (TT / TSPLIT)   // 256
#define ROW4 (HH / 4)          // 512 float4 per row
#define PARTN ((size_t)64 * NSTEP * ROW4)   // float4 elems per z-slice = 524288

// ---------------- Kernel 1: partial segment-sums, float4, T-split ----------------
// grid (2, 64, 8), block 256. Thread owns 4 h-columns; 16 float4 accumulators.
__global__ __launch_bounds__(256, 4) void k_segsum4(const float* __restrict__ hidden,
                                                    const int* __restrict__ step,
                                                    float4* __restrict__ part) {
  const int bn   = blockIdx.y;
  const int z    = blockIdx.z;
  const int col4 = blockIdx.x * 256 + threadIdx.x;   // [0, 512)
  const int t0   = z * TCHUNK;

  __shared__ int s_step[TCHUNK];
  s_step[threadIdx.x] = step[bn * TT + t0 + threadIdx.x];
  __syncthreads();

  const float4* hp = (const float4*)hidden + (size_t)(bn * TT + t0) * ROW4 + col4;

  float4 acc[NSTEP];
#pragma unroll
  for (int k = 0; k < NSTEP; ++k) acc[k] = make_float4(0.f, 0.f, 0.f, 0.f);

  for (int t = 0; t < TCHUNK; t += 8) {
    float4 v[8];
#pragma unroll
    for (int u = 0; u < 8; ++u) v[u] = hp[(size_t)(t + u) * ROW4];
#pragma unroll
    for (int u = 0; u < 8; ++u) {
      const int s = __builtin_amdgcn_readfirstlane(s_step[t + u]);
      switch (s) {
#define SEG_CASE(K) case K: acc[K].x += v[u].x; acc[K].y += v[u].y; \
                            acc[K].z += v[u].z; acc[K].w += v[u].w; break;
        SEG_CASE(0)  SEG_CASE(1)  SEG_CASE(2)  SEG_CASE(3)
        SEG_CASE(4)  SEG_CASE(5)  SEG_CASE(6)  SEG_CASE(7)
        SEG_CASE(8)  SEG_CASE(9)  SEG_CASE(10) SEG_CASE(11)
        SEG_CASE(12) SEG_CASE(13) SEG_CASE(14) SEG_CASE(15)
#undef SEG_CASE
      }
    }
  }

  float4* op = part + (size_t)z * PARTN + ((size_t)bn * NSTEP) * ROW4 + col4;
#pragma unroll
  for (int k = 0; k < NSTEP; ++k) op[(size_t)k * ROW4] = acc[k];
}

// ---------------- Kernel 1b: reduce TSPLIT partials -> ssum ----------------
__global__ __launch_bounds__(256) void k_reduce(const float4* __restrict__ part,
                                                float4* __restrict__ ssum) {
  const size_t i = (size_t)blockIdx.x * 256 + threadIdx.x;  // < PARTN
  float4 s = part[i];
#pragma unroll
  for (int z = 1; z < TSPLIT; ++z) {
    const float4 v = part[(size_t)z * PARTN + i];
    s.x += v.x; s.y += v.y; s.z += v.z; s.w += v.w;
  }
  ssum[i] = s;
}

// ---------------- Kernel 2: per-(b,n) cosine weights -> text_logits ----------------
__global__ __launch_bounds__(256) void k_bn(const float* __restrict__ pol,
                                            const float* __restrict__ refp,
                                            const int* __restrict__ step,
                                            const float* __restrict__ ssum,
                                            float* __restrict__ text_logits) {
  const int bn  = blockIdx.x;
  const int b   = bn >> 3;
  const int bn0 = b << 3;

  __shared__ float cnt[NSTEP], cnt0[NSTEP], lsum[NSTEP], wgt[NSTEP];
  if (threadIdx.x < NSTEP) {
    cnt[threadIdx.x] = 0.f; cnt0[threadIdx.x] = 0.f; lsum[threadIdx.x] = 0.f;
  }
  __syncthreads();

  for (int t = threadIdx.x; t < TT; t += 256) {
    const int s = step[bn * TT + t];
    atomicAdd(&cnt[s], 1.f);
    atomicAdd(&lsum[s], pol[bn * TT + t] - refp[bn * TT + t]);
    const int s0 = step[bn0 * TT + t];
    atomicAdd(&cnt0[s0], 1.f);
  }
  __syncthreads();

  const int wave = threadIdx.x >> 6;
  const int lane = threadIdx.x & 63;

  for (int si = 0; si < 4; ++si) {
    const int s = wave * 4 + si;
    const float c  = fmaxf(cnt[s],  1.f);
    const float c0 = fmaxf(cnt0[s], 1.f);
    const float ic  = 1.f / c;
    const float ic0 = 1.f / c0;
    const float* p  = ssum + ((size_t)bn  * NSTEP + s) * HH;
    const float* p0 = ssum + ((size_t)bn0 * NSTEP + s) * HH;
    float dot = 0.f, nn = 0.f, rr = 0.f;
    for (int h = lane; h < HH; h += 64) {
      const float a  = p[h]  * ic;
      const float r0 = p0[h] * ic0;
      dot += a * r0; nn += a * a; rr += r0 * r0;
    }
#pragma unroll
    for (int off = 32; off > 0; off >>= 1) {
      dot += __shfl_down(dot, off);
      nn  += __shfl_down(nn,  off);
      rr  += __shfl_down(rr,  off);
    }
    if (lane == 0) {
      const float nrm = fmaxf(sqrtf(nn), EPSF);
      const float rn  = fmaxf(sqrtf(rr), EPSF);
      const float cosv = dot / (nrm * rn);
      const bool valid = (cnt[s] > 0.f) && (cnt0[s] > 0.f) && (s >= 1);
      wgt[s] = valid ? (cosv + 1.f) : 0.f;
    }
  }
  __syncthreads();

  if (threadIdx.x == 0) {
    float wsum = 0.f, tw = 0.f;
#pragma unroll
    for (int s = 0; s < NSTEP; ++s) {
      const float w = wgt[s];
      wsum += w * (lsum[s] / fmaxf(cnt[s], 1.f));
      tw   += w;
    }
    text_logits[bn] = (tw > 0.f) ? (wsum / fmaxf(tw, EPSF)) : 0.f;
  }
}

// ---------------- Kernel 3: LambdaRank loss + reward means ----------------
__device__ inline float softplus_f(float x) {
  return fmaxf(x, 0.f) + log1pf(expf(-fabsf(x)));
}

__global__ __launch_bounds__(256) void k_final(const float* __restrict__ pol,
                                               const float* __restrict__ refp,
                                               const float* __restrict__ labels,
                                               const float* __restrict__ text_logits,
                                               float* __restrict__ out) {
  const int which = blockIdx.x;
  const int wave = threadIdx.x >> 6;
  const int lane = threadIdx.x & 63;
  __shared__ float red[4];

  if (which == 0) {
    float part = 0.f;
    if (threadIdx.x < 64) {
      const int b = threadIdx.x >> 3, i = threadIdx.x & 7;
      const float pi = text_logits[b * 8 + i];
      const float li = labels[b * 8 + i];
#pragma unroll
      for (int j = 0; j < 8; ++j) {
        const float ld = li - labels[b * 8 + j];
        const float sg = (ld > 0.f) ? 1.f : ((ld < 0.f) ? -1.f : 0.f);
        const float z  = (pi - text_logits[b * 8 + j]) * sg;
        part += softplus_f(-z);
      }
    }
    if (wave == 0) {
#pragma unroll
      for (int off = 32; off > 0; off >>= 1) part += __shfl_down(part, off);
      if (lane == 0) {
        const float lr = part / (56.f * 8.f);
        out[0] = softplus_f(-BETA * lr);
      }
    }
  } else {
    const int n = (which == 1) ? 0 : 7;
    float s = 0.f;
    for (int i = threadIdx.x; i < 8 * TT; i += 256) {
      const int b = i >> 11, t = i & (TT - 1);
      const size_t idx = ((size_t)(b * 8 + n)) * TT + t;
      s += pol[idx] - refp[idx];
    }
#pragma unroll
    for (int off = 32; off > 0; off >>= 1) s += __shfl_down(s, off);
    if (lane == 0) red[wave] = s;
    __syncthreads();
    if (threadIdx.x == 0)
      out[which] = (red[0] + red[1] + red[2] + red[3]) / (8.f * TT);
  }
}

extern "C" void kernel_launch(void* const* d_in, const int* in_sizes, int n_in,
                              void* d_out, int out_size, void* d_ws, size_t ws_size,
                              hipStream_t stream) {
  const float* pol    = (const float*)d_in[0];
  const float* refp   = (const float*)d_in[1];
  const float* hidden = (const float*)d_in[2];
  const int*   step   = (const int*)d_in[3];
  const float* labels = (const float*)d_in[4];
  float* out = (float*)d_out;

  float4* part = (float4*)d_ws;                              // 8 * 8MB = 64 MB
  float4* ssum4 = part + (size_t)TSPLIT * PARTN;             // 8 MB
  float*  ssum  = (float*)ssum4;
  float*  text_logits = (float*)(ssum4 + PARTN);             // 64 floats

  dim3 g1(2, 64, TSPLIT);
  k_segsum4<<<g1, 256, 0, stream>>>(hidden, step, part);
  k_reduce<<<PARTN / 256, 256, 0, stream>>>(part, ssum4);
  k_bn<<<64, 256, 0, stream>>>(pol, refp, step, ssum, text_logits);
  k_final<<<3, 256, 0, stream>>>(pol, refp, labels, text_logits, out);
}

// Round 3
// 312.989 us; speedup vs baseline: 7.8111x; 7.8111x over previous
//
#include <hip/hip_runtime.h>
#include <math.h>

#define TT 2048
#define HH 2048
#define NSTEP 16
#define EPSF 1e-8f
#define BETA 0.1f
#define TSPLIT 4
#define TCHUNK (TT / TSPLIT)                 // 512
#define ROW2 (HH / 2)                        // 1024 float2 per row
#define PART_FLOATS ((size_t)64 * NSTEP * HH)  // 2097152 floats per z-slice (8 MB)

// ---------------- Kernel 1: partial segment-sums, float2, T-split, dbuf ----------------
// grid (4, 64, TSPLIT), block 256. Thread owns 2 h-columns; 16 float2 accumulators.
__global__ __launch_bounds__(256, 4) void k_segsum2(const float* __restrict__ hidden,
                                                    const int* __restrict__ step,
                                                    float2* __restrict__ part) {
  const int bn   = blockIdx.y;
  const int z    = blockIdx.z;
  const int col2 = blockIdx.x * 256 + threadIdx.x;   // [0, 1024)
  const int t0   = z * TCHUNK;

  __shared__ int s_step[TCHUNK];
  for (int i = threadIdx.x; i < TCHUNK; i += 256) s_step[i] = step[bn * TT + t0 + i];
  __syncthreads();

  const float2* hp = (const float2*)hidden + (size_t)(bn * TT + t0) * ROW2 + col2;

  float2 acc[NSTEP];
#pragma unroll
  for (int k = 0; k < NSTEP; ++k) acc[k] = make_float2(0.f, 0.f);

  float2 va[8], vb[8];

#define LOADG(dst, base)                                        \
  _Pragma("unroll")                                             \
  for (int u = 0; u < 8; ++u) dst[u] = hp[(size_t)((base) + u) * ROW2];

#define PROC(src, base)                                                        \
  _Pragma("unroll")                                                            \
  for (int u = 0; u < 8; ++u) {                                                \
    const int s = __builtin_amdgcn_readfirstlane(s_step[(base) + u]);          \
    switch (s) {                                                               \
      case 0:  acc[0].x  += src[u].x; acc[0].y  += src[u].y; break;            \
      case 1:  acc[1].x  += src[u].x; acc[1].y  += src[u].y; break;            \
      case 2:  acc[2].x  += src[u].x; acc[2].y  += src[u].y; break;            \
      case 3:  acc[3].x  += src[u].x; acc[3].y  += src[u].y; break;            \
      case 4:  acc[4].x  += src[u].x; acc[4].y  += src[u].y; break;            \
      case 5:  acc[5].x  += src[u].x; acc[5].y  += src[u].y; break;            \
      case 6:  acc[6].x  += src[u].x; acc[6].y  += src[u].y; break;            \
      case 7:  acc[7].x  += src[u].x; acc[7].y  += src[u].y; break;            \
      case 8:  acc[8].x  += src[u].x; acc[8].y  += src[u].y; break;            \
      case 9:  acc[9].x  += src[u].x; acc[9].y  += src[u].y; break;            \
      case 10: acc[10].x += src[u].x; acc[10].y += src[u].y; break;            \
      case 11: acc[11].x += src[u].x; acc[11].y += src[u].y; break;            \
      case 12: acc[12].x += src[u].x; acc[12].y += src[u].y; break;            \
      case 13: acc[13].x += src[u].x; acc[13].y += src[u].y; break;            \
      case 14: acc[14].x += src[u].x; acc[14].y += src[u].y; break;            \
      case 15: acc[15].x += src[u].x; acc[15].y += src[u].y; break;            \
    }                                                                          \
  }

  LOADG(va, 0)
  for (int t = 0; t < TCHUNK; t += 16) {
    LOADG(vb, t + 8)
    PROC(va, t)
    if (t + 16 < TCHUNK) { LOADG(va, t + 16) }
    PROC(vb, t + 8)
  }
#undef LOADG
#undef PROC

  float2* op = (float2*)part + (size_t)z * (PART_FLOATS / 2) +
               ((size_t)bn * NSTEP) * ROW2 + col2;
#pragma unroll
  for (int k = 0; k < NSTEP; ++k) op[(size_t)k * ROW2] = acc[k];
}

// ---------------- Kernel 1b: reduce TSPLIT partials -> ssum ----------------
__global__ __launch_bounds__(256) void k_reduce(const float4* __restrict__ part,
                                                float4* __restrict__ ssum) {
  const size_t i = (size_t)blockIdx.x * 256 + threadIdx.x;   // < PART_FLOATS/4
  const size_t slice = PART_FLOATS / 4;
  float4 s = part[i];
#pragma unroll
  for (int zz = 1; zz < TSPLIT; ++zz) {
    const float4 v = part[(size_t)zz * slice + i];
    s.x += v.x; s.y += v.y; s.z += v.z; s.w += v.w;
  }
  ssum[i] = s;
}

// ---------------- Kernel 2: per-(b,n) cosine weights -> text_logits ----------------
__global__ __launch_bounds__(256) void k_bn(const float* __restrict__ pol,
                                            const float* __restrict__ refp,
                                            const int* __restrict__ step,
                                            const float* __restrict__ ssum,
                                            float* __restrict__ text_logits) {
  const int bn  = blockIdx.x;
  const int b   = bn >> 3;
  const int bn0 = b << 3;

  __shared__ float cnt[NSTEP], cnt0[NSTEP], lsum[NSTEP], wgt[NSTEP];
  if (threadIdx.x < NSTEP) {
    cnt[threadIdx.x] = 0.f; cnt0[threadIdx.x] = 0.f; lsum[threadIdx.x] = 0.f;
  }
  __syncthreads();

  for (int t = threadIdx.x; t < TT; t += 256) {
    const int s = step[bn * TT + t];
    atomicAdd(&cnt[s], 1.f);
    atomicAdd(&lsum[s], pol[bn * TT + t] - refp[bn * TT + t]);
    const int s0 = step[bn0 * TT + t];
    atomicAdd(&cnt0[s0], 1.f);
  }
  __syncthreads();

  const int wave = threadIdx.x >> 6;
  const int lane = threadIdx.x & 63;

  for (int si = 0; si < 4; ++si) {
    const int s = wave * 4 + si;
    const float c  = fmaxf(cnt[s],  1.f);
    const float c0 = fmaxf(cnt0[s], 1.f);
    const float ic  = 1.f / c;
    const float ic0 = 1.f / c0;
    const float* p  = ssum + ((size_t)bn  * NSTEP + s) * HH;
    const float* p0 = ssum + ((size_t)bn0 * NSTEP + s) * HH;
    float dot = 0.f, nn = 0.f, rr = 0.f;
    for (int h = lane; h < HH; h += 64) {
      const float a  = p[h]  * ic;
      const float r0 = p0[h] * ic0;
      dot += a * r0; nn += a * a; rr += r0 * r0;
    }
#pragma unroll
    for (int off = 32; off > 0; off >>= 1) {
      dot += __shfl_down(dot, off);
      nn  += __shfl_down(nn,  off);
      rr  += __shfl_down(rr,  off);
    }
    if (lane == 0) {
      const float nrm = fmaxf(sqrtf(nn), EPSF);
      const float rn  = fmaxf(sqrtf(rr), EPSF);
      const float cosv = dot / (nrm * rn);
      const bool valid = (cnt[s] > 0.f) && (cnt0[s] > 0.f) && (s >= 1);
      wgt[s] = valid ? (cosv + 1.f) : 0.f;
    }
  }
  __syncthreads();

  if (threadIdx.x == 0) {
    float wsum = 0.f, tw = 0.f;
#pragma unroll
    for (int s = 0; s < NSTEP; ++s) {
      const float w = wgt[s];
      wsum += w * (lsum[s] / fmaxf(cnt[s], 1.f));
      tw   += w;
    }
    text_logits[bn] = (tw > 0.f) ? (wsum / fmaxf(tw, EPSF)) : 0.f;
  }
}

// ---------------- Kernel 3: LambdaRank loss + reward means ----------------
__device__ inline float softplus_f(float x) {
  return fmaxf(x, 0.f) + log1pf(expf(-fabsf(x)));
}

__global__ __launch_bounds__(256) void k_final(const float* __restrict__ pol,
                                               const float* __restrict__ refp,
                                               const float* __restrict__ labels,
                                               const float* __restrict__ text_logits,
                                               float* __restrict__ out) {
  const int which = blockIdx.x;
  const int wave = threadIdx.x >> 6;
  const int lane = threadIdx.x & 63;
  __shared__ float red[4];

  if (which == 0) {
    float part = 0.f;
    if (threadIdx.x < 64) {
      const int b = threadIdx.x >> 3, i = threadIdx.x & 7;
      const float pi = text_logits[b * 8 + i];
      const float li = labels[b * 8 + i];
#pragma unroll
      for (int j = 0; j < 8; ++j) {
        const float ld = li - labels[b * 8 + j];
        const float sg = (ld > 0.f) ? 1.f : ((ld < 0.f) ? -1.f : 0.f);
        const float z  = (pi - text_logits[b * 8 + j]) * sg;
        part += softplus_f(-z);
      }
    }
    if (wave == 0) {
#pragma unroll
      for (int off = 32; off > 0; off >>= 1) part += __shfl_down(part, off);
      if (lane == 0) {
        const float lr = part / (56.f * 8.f);
        out[0] = softplus_f(-BETA * lr);
      }
    }
  } else {
    const int n = (which == 1) ? 0 : 7;
    float s = 0.f;
    for (int i = threadIdx.x; i < 8 * TT; i += 256) {
      const int b = i >> 11, t = i & (TT - 1);
      const size_t idx = ((size_t)(b * 8 + n)) * TT + t;
      s += pol[idx] - refp[idx];
    }
#pragma unroll
    for (int off = 32; off > 0; off >>= 1) s += __shfl_down(s, off);
    if (lane == 0) red[wave] = s;
    __syncthreads();
    if (threadIdx.x == 0)
      out[which] = (red[0] + red[1] + red[2] + red[3]) / (8.f * TT);
  }
}

extern "C" void kernel_launch(void* const* d_in, const int* in_sizes, int n_in,
                              void* d_out, int out_size, void* d_ws, size_t ws_size,
                              hipStream_t stream) {
  const float* pol    = (const float*)d_in[0];
  const float* refp   = (const float*)d_in[1];
  const float* hidden = (const float*)d_in[2];
  const int*   step   = (const int*)d_in[3];
  const float* labels = (const float*)d_in[4];
  float* out = (float*)d_out;

  float* part = (float*)d_ws;                                  // TSPLIT * 8 MB = 32 MB
  float* ssum = part + (size_t)TSPLIT * PART_FLOATS;           // 8 MB
  float* text_logits = ssum + PART_FLOATS;                     // 64 floats

  dim3 g1(4, 64, TSPLIT);
  k_segsum2<<<g1, 256, 0, stream>>>(hidden, step, (float2*)part);
  k_reduce<<<(int)(PART_FLOATS / 4 / 256), 256, 0, stream>>>((const float4*)part,
                                                             (float4*)ssum);
  k_bn<<<64, 256, 0, stream>>>(pol, refp, step, ssum, text_logits);
  k_final<<<3, 256, 0, stream>>>(pol, refp, labels, text_logits, out);
}

// Round 4
// 282.418 us; speedup vs baseline: 8.6567x; 1.1082x over previous
//
#include <hip/hip_runtime.h>
#include <math.h>

#define TT 2048
#define HH 2048
#define NSTEP 16
#define EPSF 1e-8f
#define BETA 0.1f
#define TSPLIT 4
#define TCHUNK (TT / TSPLIT)                 // 512
#define ROW2 (HH / 2)                        // 1024 float2 per row
#define PART_FLOATS ((size_t)64 * NSTEP * HH)  // floats per z-slice (8 MB)

// ---------------- Kernel 1: partial segment-sums, float2, T-split, dbuf ----------------
__global__ __launch_bounds__(256, 4) void k_segsum2(const float* __restrict__ hidden,
                                                    const int* __restrict__ step,
                                                    float2* __restrict__ part) {
  const int bn   = blockIdx.y;
  const int z    = blockIdx.z;
  const int col2 = blockIdx.x * 256 + threadIdx.x;   // [0, 1024)
  const int t0   = z * TCHUNK;

  __shared__ int s_step[TCHUNK];
  for (int i = threadIdx.x; i < TCHUNK; i += 256) s_step[i] = step[bn * TT + t0 + i];
  __syncthreads();

  const float2* hp = (const float2*)hidden + (size_t)(bn * TT + t0) * ROW2 + col2;

  float2 acc[NSTEP];
#pragma unroll
  for (int k = 0; k < NSTEP; ++k) acc[k] = make_float2(0.f, 0.f);

  float2 va[8], vb[8];

#define LOADG(dst, base)                                        \
  _Pragma("unroll")                                             \
  for (int u = 0; u < 8; ++u) dst[u] = hp[(size_t)((base) + u) * ROW2];

#define PROC(src, base)                                                        \
  _Pragma("unroll")                                                            \
  for (int u = 0; u < 8; ++u) {                                                \
    const int s = __builtin_amdgcn_readfirstlane(s_step[(base) + u]);          \
    switch (s) {                                                               \
      case 0:  acc[0].x  += src[u].x; acc[0].y  += src[u].y; break;            \
      case 1:  acc[1].x  += src[u].x; acc[1].y  += src[u].y; break;            \
      case 2:  acc[2].x  += src[u].x; acc[2].y  += src[u].y; break;            \
      case 3:  acc[3].x  += src[u].x; acc[3].y  += src[u].y; break;            \
      case 4:  acc[4].x  += src[u].x; acc[4].y  += src[u].y; break;            \
      case 5:  acc[5].x  += src[u].x; acc[5].y  += src[u].y; break;            \
      case 6:  acc[6].x  += src[u].x; acc[6].y  += src[u].y; break;            \
      case 7:  acc[7].x  += src[u].x; acc[7].y  += src[u].y; break;            \
      case 8:  acc[8].x  += src[u].x; acc[8].y  += src[u].y; break;            \
      case 9:  acc[9].x  += src[u].x; acc[9].y  += src[u].y; break;            \
      case 10: acc[10].x += src[u].x; acc[10].y += src[u].y; break;            \
      case 11: acc[11].x += src[u].x; acc[11].y += src[u].y; break;            \
      case 12: acc[12].x += src[u].x; acc[12].y += src[u].y; break;            \
      case 13: acc[13].x += src[u].x; acc[13].y += src[u].y; break;            \
      case 14: acc[14].x += src[u].x; acc[14].y += src[u].y; break;            \
      case 15: acc[15].x += src[u].x; acc[15].y += src[u].y; break;            \
    }                                                                          \
  }

  LOADG(va, 0)
  for (int t = 0; t < TCHUNK; t += 16) {
    LOADG(vb, t + 8)
    PROC(va, t)
    if (t + 16 < TCHUNK) { LOADG(va, t + 16) }
    PROC(vb, t + 8)
  }
#undef LOADG
#undef PROC

  float2* op = (float2*)part + (size_t)z * (PART_FLOATS / 2) +
               ((size_t)bn * NSTEP) * ROW2 + col2;
#pragma unroll
  for (int k = 0; k < NSTEP; ++k) op[(size_t)k * ROW2] = acc[k];
}

// ---------------- Kernel 1b: reduce TSPLIT partials -> ssum ----------------
__global__ __launch_bounds__(256) void k_reduce(const float4* __restrict__ part,
                                                float4* __restrict__ ssum) {
  const size_t i = (size_t)blockIdx.x * 256 + threadIdx.x;   // < PART_FLOATS/4
  const size_t slice = PART_FLOATS / 4;
  float4 s = part[i];
#pragma unroll
  for (int zz = 1; zz < TSPLIT; ++zz) {
    const float4 v = part[(size_t)zz * slice + i];
    s.x += v.x; s.y += v.y; s.z += v.z; s.w += v.w;
  }
  ssum[i] = s;
}

// ---------------- Kernel 2: per-(b,n) cosine weights -> text_logits ----------------
// 64 blocks x 1024 threads; wave w owns segment s=w; float4 loads, shuffle reduce.
__global__ __launch_bounds__(1024) void k_bn(const float* __restrict__ pol,
                                             const float* __restrict__ refp,
                                             const int* __restrict__ step,
                                             const float* __restrict__ ssum,
                                             float* __restrict__ text_logits) {
  const int bn  = blockIdx.x;
  const int b   = bn >> 3;
  const int bn0 = b << 3;
  const int wave = threadIdx.x >> 6;   // 0..15 == segment
  const int lane = threadIdx.x & 63;

  __shared__ float cnt[NSTEP], cnt0[NSTEP], lsum[NSTEP], wgt[NSTEP];
  if (threadIdx.x < NSTEP) {
    cnt[threadIdx.x] = 0.f; cnt0[threadIdx.x] = 0.f; lsum[threadIdx.x] = 0.f;
  }
  __syncthreads();

  // counts + logit sums (2 elements per thread)
  for (int t = threadIdx.x; t < TT; t += 1024) {
    const int s = step[bn * TT + t];
    atomicAdd(&cnt[s], 1.f);
    atomicAdd(&lsum[s], pol[bn * TT + t] - refp[bn * TT + t]);
    const int s0 = step[bn0 * TT + t];
    atomicAdd(&cnt0[s0], 1.f);
  }
  __syncthreads();

  // cosine per segment (one wave each), float4 loads: 8 per lane per array
  const int s = wave;
  const float c  = fmaxf(cnt[s],  1.f);
  const float c0 = fmaxf(cnt0[s], 1.f);
  const float ic  = 1.f / c;
  const float ic0 = 1.f / c0;
  const float4* p  = (const float4*)(ssum + ((size_t)bn  * NSTEP + s) * HH);
  const float4* p0 = (const float4*)(ssum + ((size_t)bn0 * NSTEP + s) * HH);

  float dot = 0.f, nn = 0.f, rr = 0.f;
#pragma unroll
  for (int i = 0; i < 8; ++i) {
    const float4 a4 = p[lane + i * 64];
    const float4 r4 = p0[lane + i * 64];
    const float ax = a4.x * ic, ay = a4.y * ic, az = a4.z * ic, aw = a4.w * ic;
    const float rx = r4.x * ic0, ry = r4.y * ic0, rz = r4.z * ic0, rw = r4.w * ic0;
    dot += ax * rx + ay * ry + az * rz + aw * rw;
    nn  += ax * ax + ay * ay + az * az + aw * aw;
    rr  += rx * rx + ry * ry + rz * rz + rw * rw;
  }
#pragma unroll
  for (int off = 32; off > 0; off >>= 1) {
    dot += __shfl_down(dot, off);
    nn  += __shfl_down(nn,  off);
    rr  += __shfl_down(rr,  off);
  }
  if (lane == 0) {
    const float nrm = fmaxf(sqrtf(nn), EPSF);
    const float rn  = fmaxf(sqrtf(rr), EPSF);
    const float cosv = dot / (nrm * rn);
    const bool valid = (cnt[s] > 0.f) && (cnt0[s] > 0.f) && (s >= 1);
    wgt[s] = valid ? (cosv + 1.f) : 0.f;
  }
  __syncthreads();

  if (threadIdx.x == 0) {
    float wsum = 0.f, tw = 0.f;
#pragma unroll
    for (int k = 0; k < NSTEP; ++k) {
      const float w = wgt[k];
      wsum += w * (lsum[k] / fmaxf(cnt[k], 1.f));
      tw   += w;
    }
    text_logits[bn] = (tw > 0.f) ? (wsum / fmaxf(tw, EPSF)) : 0.f;
  }
}

// ---------------- Kernel 3: LambdaRank loss + reward means ----------------
__device__ inline float softplus_f(float x) {
  return fmaxf(x, 0.f) + log1pf(expf(-fabsf(x)));
}

__global__ __launch_bounds__(256) void k_final(const float* __restrict__ pol,
                                               const float* __restrict__ refp,
                                               const float* __restrict__ labels,
                                               const float* __restrict__ text_logits,
                                               float* __restrict__ out) {
  const int which = blockIdx.x;
  const int wave = threadIdx.x >> 6;
  const int lane = threadIdx.x & 63;
  __shared__ float red[4];

  if (which == 0) {
    float part = 0.f;
    if (threadIdx.x < 64) {
      const int b = threadIdx.x >> 3, i = threadIdx.x & 7;
      const float pi = text_logits[b * 8 + i];
      const float li = labels[b * 8 + i];
#pragma unroll
      for (int j = 0; j < 8; ++j) {
        const float ld = li - labels[b * 8 + j];
        const float sg = (ld > 0.f) ? 1.f : ((ld < 0.f) ? -1.f : 0.f);
        const float z  = (pi - text_logits[b * 8 + j]) * sg;
        part += softplus_f(-z);
      }
    }
    if (wave == 0) {
#pragma unroll
      for (int off = 32; off > 0; off >>= 1) part += __shfl_down(part, off);
      if (lane == 0) {
        const float lr = part / (56.f * 8.f);
        out[0] = softplus_f(-BETA * lr);
      }
    }
  } else {
    const int n = (which == 1) ? 0 : 7;
    float s = 0.f;
    for (int i = threadIdx.x; i < 8 * TT; i += 256) {
      const int b = i >> 11, t = i & (TT - 1);
      const size_t idx = ((size_t)(b * 8 + n)) * TT + t;
      s += pol[idx] - refp[idx];
    }
#pragma unroll
    for (int off = 32; off > 0; off >>= 1) s += __shfl_down(s, off);
    if (lane == 0) red[wave] = s;
    __syncthreads();
    if (threadIdx.x == 0)
      out[which] = (red[0] + red[1] + red[2] + red[3]) / (8.f * TT);
  }
}

extern "C" void kernel_launch(void* const* d_in, const int* in_sizes, int n_in,
                              void* d_out, int out_size, void* d_ws, size_t ws_size,
                              hipStream_t stream) {
  const float* pol    = (const float*)d_in[0];
  const float* refp   = (const float*)d_in[1];
  const float* hidden = (const float*)d_in[2];
  const int*   step   = (const int*)d_in[3];
  const float* labels = (const float*)d_in[4];
  float* out = (float*)d_out;

  float* part = (float*)d_ws;                                  // TSPLIT * 8 MB
  float* ssum = part + (size_t)TSPLIT * PART_FLOATS;           // 8 MB
  float* text_logits = ssum + PART_FLOATS;                     // 64 floats

  dim3 g1(4, 64, TSPLIT);
  k_segsum2<<<g1, 256, 0, stream>>>(hidden, step, (float2*)part);
  k_reduce<<<(int)(PART_FLOATS / 4 / 256), 256, 0, stream>>>((const float4*)part,
                                                             (float4*)ssum);
  k_bn<<<64, 1024, 0, stream>>>(pol, refp, step, ssum, text_logits);
  k_final<<<3, 256, 0, stream>>>(pol, refp, labels, text_logits, out);
}